// Round 17
// baseline (389.559 us; speedup 1.0000x reference)
//
#include <hip/hip_runtime.h>
#include <hip/hip_bf16.h>

#define NN0 200000
#define NN1 50000
#define NN2 10000
#define IN_DIM 512
#define HD 256
#define OUT_D 128
#define CH0 ((NN1+1023)/1024)   // 49 scan chunks, graph0
#define CH1 ((NN2+1023)/1024)   // 10 scan chunks, graph1

typedef unsigned short u16;
typedef unsigned int u32;
typedef __attribute__((ext_vector_type(8))) short s16x8;
typedef __attribute__((ext_vector_type(4))) float f32x4;
typedef __attribute__((ext_vector_type(4))) u32 u32x4;

__device__ __forceinline__ float b2f(u16 u){ return __uint_as_float(((u32)u)<<16); }
__device__ __forceinline__ u16 f2b(float f){
  u32 x = __float_as_uint(f);
  u32 r = x + 0x7fffu + ((x>>16)&1u);
  return (u16)(r>>16);
}
// packed f32x2 -> bf16x2 (R11/R12 A/B: cvtpk beat scalar by 12us)
__device__ __forceinline__ u32 cvtpk(float a, float b){
  u32 r;
  asm("v_cvt_pk_bf16_f32 %0, %1, %2" : "=v"(r) : "v"(a), "v"(b));
  return r;
}

__device__ __forceinline__ void gl_lds16(const void* g, void* l){
  __builtin_amdgcn_global_load_lds((const __attribute__((address_space(1))) u32*)g,
                                   (__attribute__((address_space(3))) u32*)l, 16, 0, 0);
}

// ---- fused: zero counter region + pack weights ----
__device__ __forceinline__ void pack_one(const float* __restrict__ W, u16* __restrict__ out,
                                         int K, int N, int c){
  int lane = c & 63;
  int f = (c >> 6) % (N>>4);
  int s = (c >> 6) / (N>>4);
  int col = f*16 + (lane & 15);
  int k0 = s*32 + (lane >> 4)*8;
  u16* o = out + (size_t)c*8;
  #pragma unroll
  for (int e = 0; e < 8; ++e) o[e] = f2b(W[(size_t)(k0+e)*N + col]);
}

__global__ void wpz_kernel(int4* __restrict__ zp, int n16, int nzb,
                           const float* W1, u16* P1, const float* Wc, u16* Pc,
                           const float* Wo, u16* Po){
  int b = blockIdx.x;
  if (b < nzb){
    int i = b*256 + threadIdx.x;
    if (i < n16) zp[i] = make_int4(0,0,0,0);
  } else {
    int c = (b - nzb)*256 + threadIdx.x;
    if (c < 16384)      pack_one(W1, P1, IN_DIM, HD, c);
    else if (c < 24576) pack_one(Wc, Pc, HD, HD, c - 16384);
    else if (c < 28672) pack_one(Wo, Po, HD, OUT_D, c - 24576);
  }
}

// ---- scan partials (two-level scan, level 1) ----
__global__ __launch_bounds__(1024) void scan_part(
    const int* __restrict__ c0, int* __restrict__ o0,
    const int* __restrict__ c1, int* __restrict__ o1, int* __restrict__ bsum)
{
  __shared__ int wsum[16];
  int b = blockIdx.x;
  const int* cnt; int* off; int n, base, slot;
  if (b < CH0){ cnt = c0; off = o0; n = NN1; base = b*1024; slot = b; }
  else        { int bb = b - CH0; cnt = c1; off = o1; n = NN2; base = bb*1024; slot = CH0 + bb; }
  int tid = threadIdx.x, lane = tid & 63, wv = tid >> 6;
  int i = base + tid;
  int v = (i < n) ? cnt[i] : 0;
  int x = v;
  #pragma unroll
  for (int d = 1; d < 64; d <<= 1){
    int y = __shfl_up(x, d);
    if (lane >= d) x += y;
  }
  if (lane == 63) wsum[wv] = x;
  __syncthreads();
  if (wv == 0){
    int s = (lane < 16) ? wsum[lane] : 0;
    #pragma unroll
    for (int d = 1; d < 16; d <<= 1){
      int y = __shfl_up(s, d);
      if (lane >= d) s += y;
    }
    if (lane < 16) wsum[lane] = s;
  }
  __syncthreads();
  int wbase = wv ? wsum[wv-1] : 0;
  if (i < n) off[i] = wbase + x - v;
  if (tid == 0) bsum[slot] = wsum[15];
}

// ---- scan_add with inlined chunk-base scan ----
__global__ __launch_bounds__(1024) void scan_add(int* __restrict__ o0, int* __restrict__ u0,
                                                 int* __restrict__ o1, int* __restrict__ u1,
                                                 const int* __restrict__ bsum){
  __shared__ int cbs;
  int b = blockIdx.x;
  int tid = threadIdx.x, lane = tid & 63, wv = tid >> 6;
  if (wv == 0){
    int v0 = (lane < CH0) ? bsum[lane] : 0;
    int x0 = v0;
    #pragma unroll
    for (int d = 1; d < 64; d <<= 1){ int y = __shfl_up(x0, d); if (lane >= d) x0 += y; }
    int v1 = (lane < CH1) ? bsum[CH0 + lane] : 0;
    int x1 = v1;
    #pragma unroll
    for (int d = 1; d < 64; d <<= 1){ int y = __shfl_up(x1, d); if (lane >= d) x1 += y; }
    int base = (b < CH0) ? __shfl(x0 - v0, b) : __shfl(x1 - v1, b - CH0);
    if (lane == 0) cbs = base;
    if (b == 0){
      if (lane == CH0-1) o0[NN1] = x0;
      if (lane == CH1-1) o1[NN2] = x1;
    }
  }
  __syncthreads();
  int base = cbs;
  int* off; int* cur; int n, i0;
  if (b < CH0){ off = o0; cur = u0; n = NN1; i0 = b*1024; }
  else        { off = o1; cur = u1; n = NN2; i0 = (b-CH0)*1024; }
  int i = i0 + tid;
  if (i < n){
    int t = off[i] + base;
    off[i] = t; cur[i] = t;
  }
}

// ---- fused CSR fill; computes out-scale inline from outc (no separate scale pass) ----
__global__ void fill2_kernel(const int* __restrict__ s0, const int* __restrict__ d0, int E0,
                             int* __restrict__ cur0, int2* __restrict__ l0, const int* __restrict__ oc0,
                             const int* __restrict__ s1, const int* __restrict__ d1, int E1,
                             int* __restrict__ cur1, int2* __restrict__ l1, const int* __restrict__ oc1){
  int i = blockIdx.x*blockDim.x + threadIdx.x;
  if (i < E0){
    int s = s0[i];
    int c = oc0[s];
    float sc = rsqrtf((float)(c > 1 ? c : 1));
    int p = atomicAdd(&cur0[d0[i]], 1);
    l0[p] = make_int2(s, __float_as_int(sc));
  }
  if (i < E1){
    int s = s1[i];
    int c = oc1[s];
    float sc = rsqrtf((float)(c > 1 ? c : 1));
    int p = atomicAdd(&cur1[d1[i]], 1);
    l1[p] = make_int2(s, __float_as_int(sc));
  }
}

// ---- MFMA GEMM, glds staging, counted-vmcnt pipeline ----
// BKT=64 everywhere: the BKT=32 f32 swizzle measured 6.4M LDS bank conflicts
// (R16 profile); BKT=64 measured 0 (R5/R8). Optional LN epilogue (LNEP) and
// deg-count tail blocks (DEGT, R14-proven: tail placement, not head).
template<int K, int N, int BN, int BKT, int TH, bool ABF, bool RELU, bool OBF, bool LNEP, bool DEGT>
__global__ __launch_bounds__(TH) void gemm_glds(const void* __restrict__ Av,
    const u16* __restrict__ BPK, const float* __restrict__ bias,
    void* __restrict__ Cv, int M,
    const float* __restrict__ lng, const float* __restrict__ lnb,
    const int* __restrict__ gs0, const int* __restrict__ gd0, int dE0,
    const int* __restrict__ gs1, const int* __restrict__ gd1, int dE1,
    int* __restrict__ doc0, int* __restrict__ dic0,
    int* __restrict__ doc1, int* __restrict__ dic1, int gemmBlocks)
{
  constexpr int ESZ   = ABF ? 2 : 4;
  constexpr int SLOTS = (BKT*ESZ)/16;      // 16B slots per row
  constexpr int SMSK  = SLOTS - 1;
  constexpr int ROWB  = BKT*ESZ;
  constexpr int TILEB = 128*BKT*ESZ;
  constexpr int NWV   = TH/64;
  constexpr int IW    = TILEB/1024/NWV;    // glds per wave per stage
  constexpr int NT    = K/BKT;
  constexpr int NKH   = BKT/32;            // 32-k steps per tile
  constexpr int NF16  = N/16;
  constexpr int NYB   = N/BN;
  constexpr int WCN   = TH/128;            // waves in col dim
  constexpr int CST   = BN + 8;            // epilogue LDS row stride (u16)
  constexpr int EPB   = (LNEP || OBF) ? 128*CST*2 : 0;
  constexpr int LDSB  = (2*TILEB > EPB) ? 2*TILEB : EPB;
  __shared__ char smem[LDSB];

  if (DEGT && (int)blockIdx.x >= gemmBlocks){
    int i = ((int)blockIdx.x - gemmBlocks)*TH + threadIdx.x;
    if (i < dE0){ atomicAdd(&doc0[gs0[i]], 1); atomicAdd(&dic0[gd0[i]], 1); }
    if (i < dE1){ atomicAdd(&doc1[gs1[i]], 1); atomicAdd(&dic1[gd1[i]], 1); }
    return;
  }

  const int t = threadIdx.x;
  const int lane = t & 63;
  const int wv = t >> 6;
  const int wr = wv / WCN, wc = wv % WCN;

  int b;
  {
    int nb = DEGT ? gemmBlocks : (int)gridDim.x;
    int h = blockIdx.x;
    if (nb >= 8){
      int q = nb >> 3, r = nb & 7, k = h & 7, pos = h >> 3;
      b = (k < r ? k*(q+1) : r*(q+1) + (k-r)*q) + pos;
    } else b = h;
  }
  const int by = b % NYB;
  const int r0 = (b / NYB) * 128;
  const int c0 = by * BN;
  const int m15 = lane & 15, kg = lane >> 4;

  auto stage = [&](int buf, int ti){
    const int k0 = ti*BKT;
    char* bb = smem + buf*TILEB;
    #pragma unroll
    for (int s = 0; s < IW; ++s){
      int i16 = (wv*IW + s)*64 + lane;
      int row = i16 / SLOTS;
      int tt  = i16 & SMSK;
      int tsrc = tt ^ (row & SMSK);
      int grc = min(r0 + row, M-1);
      const char* g = (const char*)Av + ((size_t)grc*K + k0)*ESZ + tsrc*16;
      gl_lds16(g, bb + (wv*IW + s)*1024);
    }
  };

  f32x4 acc[4][4] = {};

  stage(0, 0);

  for (int ti = 0; ti < NT; ++ti){
    s16x8 bfr[NKH][4];
    #pragma unroll
    for (int kh = 0; kh < NKH; ++kh)
      #pragma unroll
      for (int j = 0; j < 4; ++j)
        bfr[kh][j] = *(const s16x8*)(BPK +
          (((size_t)(ti*NKH+kh)*NF16 + (c0>>4) + wc*4 + j)*64 + lane)*8);
    __builtin_amdgcn_sched_barrier(0);

    if (ti + 1 < NT) stage((ti+1)&1, ti+1);
    __builtin_amdgcn_sched_barrier(0);

    // wait for stage(ti); stage(ti+1) + this iter's bfr stay outstanding
    if (ti + 1 < NT){
      constexpr int VW = NKH*4 + IW;
      if constexpr (VW == 8)  asm volatile("s_waitcnt vmcnt(8)");
      else if constexpr (VW == 10) asm volatile("s_waitcnt vmcnt(10)");
      else if constexpr (VW == 12) asm volatile("s_waitcnt vmcnt(12)");
      else if constexpr (VW == 16) asm volatile("s_waitcnt vmcnt(16)");
      else asm volatile("s_waitcnt vmcnt(0)");
    } else {
      constexpr int VB = NKH*4;
      if constexpr (VB == 4) asm volatile("s_waitcnt vmcnt(4)");
      else                   asm volatile("s_waitcnt vmcnt(8)");
    }
    __builtin_amdgcn_s_barrier();
    __builtin_amdgcn_sched_barrier(0);

    const char* bb = smem + (ti&1)*TILEB;
    s16x8 afr[NKH][4];
    #pragma unroll
    for (int kh = 0; kh < NKH; ++kh){
      #pragma unroll
      for (int i = 0; i < 4; ++i){
        int row_l = wr*64 + i*16 + m15;
        if (ABF){
          int s = kh*4 + kg;
          int sw = s ^ (row_l & SMSK);
          afr[kh][i] = *(const s16x8*)(bb + row_l*ROWB + sw*16);
        } else {
          int s0 = kh*8 + kg*2;
          int sw0 = s0 ^ (row_l & SMSK);
          int sw1 = (s0+1) ^ (row_l & SMSK);
          float4 lo = *(const float4*)(bb + row_l*ROWB + sw0*16);
          float4 hi = *(const float4*)(bb + row_l*ROWB + sw1*16);
          u32x4 w;
          w[0] = cvtpk(lo.x, lo.y);
          w[1] = cvtpk(lo.z, lo.w);
          w[2] = cvtpk(hi.x, hi.y);
          w[3] = cvtpk(hi.z, hi.w);
          afr[kh][i] = __builtin_bit_cast(s16x8, w);
        }
      }
    }

    #pragma unroll
    for (int kh = 0; kh < NKH; ++kh)
      #pragma unroll
      for (int i = 0; i < 4; ++i)
        #pragma unroll
        for (int j = 0; j < 4; ++j)
          acc[i][j] = __builtin_amdgcn_mfma_f32_16x16x32_bf16(afr[kh][i], bfr[kh][j], acc[i][j], 0, 0, 0);

    __builtin_amdgcn_sched_barrier(0);
    __builtin_amdgcn_s_barrier();
  }

  __syncthreads();

  if constexpr (LNEP){
    // conv1+LN: repack full 256-col rows into LDS, LN per row, write bf16
    u16* cs = (u16*)smem;
    #pragma unroll
    for (int j = 0; j < 4; ++j){
      int colL = wc*64 + j*16 + m15;
      float bv = bias[colL];
      #pragma unroll
      for (int i = 0; i < 4; ++i){
        int rl = wr*64 + i*16 + kg*4;
        #pragma unroll
        for (int q = 0; q < 4; ++q){
          float v = acc[i][j][q] + bv;
          if (RELU) v = fmaxf(v, 0.f);
          cs[(rl+q)*CST + colL] = f2b(v);
        }
      }
    }
    __syncthreads();
    float4 gv = ((const float4*)lng)[lane];
    float4 bvv = ((const float4*)lnb)[lane];
    constexpr int RPW = 128/NWV;
    #pragma unroll 4
    for (int rr = 0; rr < RPW; ++rr){
      int row = wv*RPW + rr;
      ushort4 u = *(const ushort4*)&cs[row*CST + lane*4];
      float x0=b2f(u.x), x1=b2f(u.y), x2=b2f(u.z), x3=b2f(u.w);
      float s = x0+x1+x2+x3;
      #pragma unroll
      for (int d=1; d<64; d<<=1) s += __shfl_xor(s, d);
      float mu = s * (1.f/256.f);
      float e0=x0-mu, e1=x1-mu, e2=x2-mu, e3=x3-mu;
      float vv = e0*e0 + e1*e1 + e2*e2 + e3*e3;
      #pragma unroll
      for (int d=1; d<64; d<<=1) vv += __shfl_xor(vv, d);
      float inv = rsqrtf(vv*(1.f/256.f) + 1e-5f);
      int gr = r0 + row;
      if (gr < M){
        ushort4 o;
        o.x = f2b(e0*inv*gv.x + bvv.x);
        o.y = f2b(e1*inv*gv.y + bvv.y);
        o.z = f2b(e2*inv*gv.z + bvv.z);
        o.w = f2b(e3*inv*gv.w + bvv.w);
        *(ushort4*)((u16*)Cv + (size_t)gr*256 + lane*4) = o;
      }
    }
  } else if constexpr (OBF){
    // repack epilogue: acc -> LDS u16 [128][CST] -> coalesced 128B/thread stores
    u16* cs = (u16*)smem;
    #pragma unroll
    for (int j = 0; j < 4; ++j){
      int colL = wc*64 + j*16 + m15;
      float bv = bias[c0 + colL];
      #pragma unroll
      for (int i = 0; i < 4; ++i){
        int rl = wr*64 + i*16 + kg*4;
        #pragma unroll
        for (int q = 0; q < 4; ++q){
          float v = acc[i][j][q] + bv;
          if (RELU) v = fmaxf(v, 0.f);
          cs[(rl+q)*CST + colL] = f2b(v);
        }
      }
    }
    __syncthreads();
    constexpr int QPR = BN/64;               // 64-col segments per row
    int rr = t / QPR, hh = t % QPR;
    int go = r0 + rr;
    if (go < M){
      u16* dst = (u16*)Cv + (size_t)go*N + c0 + hh*64;
      const u16* sp = &cs[rr*CST + hh*64];
      #pragma unroll
      for (int c = 0; c < 8; ++c) *(s16x8*)(dst + c*8) = *(const s16x8*)(sp + c*8);
    }
  } else {
    #pragma unroll
    for (int j = 0; j < 4; ++j){
      int colg = c0 + wc*64 + j*16 + m15;
      float bv = bias[colg];
      #pragma unroll
      for (int i = 0; i < 4; ++i){
        int rbase = r0 + wr*64 + i*16 + kg*4;
        #pragma unroll
        for (int q = 0; q < 4; ++q){
          int row = rbase + q;
          if (row < M){
            float v = acc[i][j][q] + bv;
            if (RELU) v = fmaxf(v, 0.f);
            ((float*)Cv)[(size_t)row*N + colg] = v;
          }
        }
      }
    }
  }
}

// ---- CSR pull aggregation: (src,scale) pairs, 8x-unrolled; ri computed from inc ----
__global__ __launch_bounds__(256) void agg_kernel(const u16* __restrict__ X,
    const int* __restrict__ off, const int2* __restrict__ lst,
    const int* __restrict__ inc, u16* __restrict__ out, int nd)
{
  int lane = threadIdx.x & 63, wv = threadIdx.x >> 6;
  int d = blockIdx.x*4 + wv;
  if (d >= nd) return;
  int e0 = off[d], e1 = off[d+1];
  float a0=0.f, a1=0.f, a2=0.f, a3=0.f;
  int e = e0;
  for (; e + 8 <= e1; e += 8){
    int2 pp[8];
    #pragma unroll
    for (int u = 0; u < 8; ++u) pp[u] = lst[e+u];
    ushort4 uu[8];
    #pragma unroll
    for (int u = 0; u < 8; ++u) uu[u] = ((const ushort4*)X)[(size_t)pp[u].x*64 + lane];
    #pragma unroll
    for (int u = 0; u < 8; ++u){
      float sc = __int_as_float(pp[u].y);
      a0 = fmaf(b2f(uu[u].x), sc, a0);
      a1 = fmaf(b2f(uu[u].y), sc, a1);
      a2 = fmaf(b2f(uu[u].z), sc, a2);
      a3 = fmaf(b2f(uu[u].w), sc, a3);
    }
  }
  for (; e < e1; ++e){
    int2 pp = lst[e];
    float sc = __int_as_float(pp.y);
    ushort4 u = ((const ushort4*)X)[(size_t)pp.x*64 + lane];
    a0 = fmaf(b2f(u.x), sc, a0);
    a1 = fmaf(b2f(u.y), sc, a1);
    a2 = fmaf(b2f(u.z), sc, a2);
    a3 = fmaf(b2f(u.w), sc, a3);
  }
  int c = inc[d];
  float r = rsqrtf((float)(c > 1 ? c : 1));
  ushort4 o;
  o.x = f2b(a0*r); o.y = f2b(a1*r); o.z = f2b(a2*r); o.w = f2b(a3*r);
  ((ushort4*)out)[(size_t)d*64 + lane] = o;
}

// ---- row L2-normalize, 128 cols ----
__global__ __launch_bounds__(256) void rownorm_kernel(const float* __restrict__ T,
    float* __restrict__ out, int n)
{
  int lane = threadIdx.x & 63, wv = threadIdx.x >> 6;
  int r = blockIdx.x*4 + wv;
  if (r >= n) return;
  float2 x = ((const float2*)T)[(size_t)r*64 + lane];
  float s = x.x*x.x + x.y*x.y;
  #pragma unroll
  for (int d=1; d<64; d<<=1) s += __shfl_xor(s, d);
  float nrm = sqrtf(s);
  float sc = 1.f / fmaxf(nrm, 1e-12f);
  float2 o; o.x = x.x*sc; o.y = x.y*sc;
  ((float2*)out)[(size_t)r*64 + lane] = o;
}

extern "C" void kernel_launch(void* const* d_in, const int* in_sizes, int n_in,
                              void* d_out, int out_size, void* d_ws, size_t ws_size,
                              hipStream_t stream)
{
  const float* feats = (const float*)d_in[0];
  const int*   b0s   = (const int*)d_in[1];
  const int*   b0d   = (const int*)d_in[2];
  const int*   b1s   = (const int*)d_in[3];
  const int*   b1d   = (const int*)d_in[4];
  const float* W1    = (const float*)d_in[5];
  const float* bias1 = (const float*)d_in[6];
  const float* Wc    = (const float*)d_in[7];
  const float* bc    = (const float*)d_in[8];
  const float* lng   = (const float*)d_in[9];
  const float* lnb   = (const float*)d_in[10];
  const float* Wo    = (const float*)d_in[11];
  const float* bo    = (const float*)d_in[12];
  const int E0 = in_sizes[1];
  const int E1 = in_sizes[3];
  (void)n_in; (void)out_size; (void)ws_size;

  char* p = (char*)d_ws;
  auto alloc = [&](size_t bytes)->void*{ void* q = (void*)p; p += (bytes + 255) & ~(size_t)255; return q; };
  u16*   g1   = (u16*)  alloc((size_t)NN0*HD*2);
  u16*   hb   = (u16*)  alloc((size_t)NN1*HD*2);
  u16*   ag2  = (u16*)  alloc((size_t)NN2*HD*2);
  float* c2   = (float*)alloc((size_t)NN2*OUT_D*4);
  u16*   W1P  = (u16*)  alloc((size_t)HD*IN_DIM*2);
  u16*   WcP  = (u16*)  alloc((size_t)HD*HD*2);
  u16*   WoP  = (u16*)  alloc((size_t)OUT_D*HD*2);
  char* cnt_begin = p;
  int* outc0 = (int*)alloc((size_t)NN0*4);
  int* inc0  = (int*)alloc((size_t)NN1*4);
  int* outc1 = (int*)alloc((size_t)NN1*4);
  int* inc1  = (int*)alloc((size_t)NN2*4);
  char* cnt_end = p;
  int* off0  = (int*)alloc((size_t)(NN1+1)*4);
  int* cur0  = (int*)alloc((size_t)NN1*4);
  int* off1  = (int*)alloc((size_t)(NN2+1)*4);
  int* cur1  = (int*)alloc((size_t)NN2*4);
  int2* lst0 = (int2*)alloc((size_t)800000*8);
  int2* lst1 = (int2*)alloc((size_t)160000*8);
  int* bsum  = (int*)alloc((size_t)(CH0+CH1)*4);

  // K1: zero counters + pack weights
  {
    int nbytes = (int)(cnt_end - cnt_begin);
    int n16 = nbytes >> 4;
    int nzb = (n16 + 255)/256;
    wpz_kernel<<<nzb + 112, 256, 0, stream>>>((int4*)cnt_begin, n16, nzb,
                                              W1, W1P, Wc, WcP, Wo, WoP);
  }

  // K2: GEMM1 (blocks [0,nblk)) + deg-count tail (blocks [nblk, nblk+degBlocks))
  {
    int Emax = E0 > E1 ? E0 : E1;
    int degBlocks = (Emax + 255)/256;
    int nblk = ((NN0+127)/128) * (HD/128);
    gemm_glds<IN_DIM, HD, 128, 64, 256, false, false, true, false, true>
      <<<nblk + degBlocks, 256, 0, stream>>>(feats, W1P, bias1, g1, NN0,
        nullptr, nullptr, b0s, b0d, E0, b1s, b1d, E1,
        outc0, inc0, outc1, inc1, nblk);
  }

  // K3: scan partials
  scan_part<<<CH0+CH1, 1024, 0, stream>>>(inc0, off0, inc1, off1, bsum);

  // K4: add chunk bases
  scan_add<<<CH0+CH1, 1024, 0, stream>>>(off0, cur0, off1, cur1, bsum);

  // K5: CSR fill (out-scale computed inline from outc)
  {
    int Emax = E0 > E1 ? E0 : E1;
    fill2_kernel<<<(Emax+255)/256, 256, 0, stream>>>(b0s, b0d, E0, cur0, lst0, outc0,
                                                     b1s, b1d, E1, cur1, lst1, outc1);
  }

  // K6: agg1 -> hb  (ri from inc0 inline)
  agg_kernel<<<(NN1+3)/4, 256, 0, stream>>>(g1, off0, lst0, inc0, hb, NN1);

  // K7: conv1 = relu(agg1 @ Wc + bc) with fused LayerNorm -> g1
  {
    int nblk = (NN1+127)/128;
    gemm_glds<HD, HD, 256, 64, 512, true, true, false, true, false>
      <<<nblk, 512, 0, stream>>>(hb, WcP, bc, g1, NN1, lng, lnb,
        nullptr, nullptr, 0, nullptr, nullptr, 0,
        nullptr, nullptr, nullptr, nullptr, 0);
  }

  // K8: agg2 -> ag2  (ri from inc1 inline)
  agg_kernel<<<(NN2+3)/4, 256, 0, stream>>>(g1, off1, lst1, inc1, ag2, NN2);

  // K9: conv2 = agg2 @ Wo + bo -> c2 (f32)
  {
    int nblk = (NN2+127)/128;
    gemm_glds<HD, OUT_D, 128, 64, 256, true, false, false, false, false>
      <<<nblk, 256, 0, stream>>>(ag2, WoP, bo, c2, NN2, nullptr, nullptr,
        nullptr, nullptr, 0, nullptr, nullptr, 0,
        nullptr, nullptr, nullptr, nullptr, 0);
  }

  // K10: row L2 normalize -> d_out
  rownorm_kernel<<<(NN2+3)/4, 256, 0, stream>>>(c2, (float*)d_out, NN2);
}

// Round 18
// 383.448 us; speedup vs baseline: 1.0159x; 1.0159x over previous
//
#include <hip/hip_runtime.h>
#include <hip/hip_bf16.h>

#define NN0 200000
#define NN1 50000
#define NN2 10000
#define IN_DIM 512
#define HD 256
#define OUT_D 128
#define CH0 ((NN1+1023)/1024)   // 49 scan chunks, graph0
#define CH1 ((NN2+1023)/1024)   // 10 scan chunks, graph1

typedef unsigned short u16;
typedef unsigned int u32;
typedef __attribute__((ext_vector_type(8))) short s16x8;
typedef __attribute__((ext_vector_type(4))) float f32x4;
typedef __attribute__((ext_vector_type(4))) u32 u32x4;

__device__ __forceinline__ float b2f(u16 u){ return __uint_as_float(((u32)u)<<16); }
__device__ __forceinline__ u16 f2b(float f){
  u32 x = __float_as_uint(f);
  u32 r = x + 0x7fffu + ((x>>16)&1u);
  return (u16)(r>>16);
}
// packed f32x2 -> bf16x2 (R11/R12 A/B: cvtpk beat scalar by 12us)
__device__ __forceinline__ u32 cvtpk(float a, float b){
  u32 r;
  asm("v_cvt_pk_bf16_f32 %0, %1, %2" : "=v"(r) : "v"(a), "v"(b));
  return r;
}

__device__ __forceinline__ void gl_lds16(const void* g, void* l){
  __builtin_amdgcn_global_load_lds((const __attribute__((address_space(1))) u32*)g,
                                   (__attribute__((address_space(3))) u32*)l, 16, 0, 0);
}

// ---- fused: zero counter region + pack weights ----
__device__ __forceinline__ void pack_one(const float* __restrict__ W, u16* __restrict__ out,
                                         int K, int N, int c){
  int lane = c & 63;
  int f = (c >> 6) % (N>>4);
  int s = (c >> 6) / (N>>4);
  int col = f*16 + (lane & 15);
  int k0 = s*32 + (lane >> 4)*8;
  u16* o = out + (size_t)c*8;
  #pragma unroll
  for (int e = 0; e < 8; ++e) o[e] = f2b(W[(size_t)(k0+e)*N + col]);
}

__global__ void wpz_kernel(int4* __restrict__ zp, int n16, int nzb,
                           const float* W1, u16* P1, const float* Wc, u16* Pc,
                           const float* Wo, u16* Po){
  int b = blockIdx.x;
  if (b < nzb){
    int i = b*256 + threadIdx.x;
    if (i < n16) zp[i] = make_int4(0,0,0,0);
  } else {
    int c = (b - nzb)*256 + threadIdx.x;
    if (c < 16384)      pack_one(W1, P1, IN_DIM, HD, c);
    else if (c < 24576) pack_one(Wc, Pc, HD, HD, c - 16384);
    else if (c < 28672) pack_one(Wo, Po, HD, OUT_D, c - 24576);
  }
}

// ---- scan partials (two-level scan, level 1) ----
__global__ __launch_bounds__(1024) void scan_part(
    const int* __restrict__ c0, int* __restrict__ o0,
    const int* __restrict__ c1, int* __restrict__ o1, int* __restrict__ bsum)
{
  __shared__ int wsum[16];
  int b = blockIdx.x;
  const int* cnt; int* off; int n, base, slot;
  if (b < CH0){ cnt = c0; off = o0; n = NN1; base = b*1024; slot = b; }
  else        { int bb = b - CH0; cnt = c1; off = o1; n = NN2; base = bb*1024; slot = CH0 + bb; }
  int tid = threadIdx.x, lane = tid & 63, wv = tid >> 6;
  int i = base + tid;
  int v = (i < n) ? cnt[i] : 0;
  int x = v;
  #pragma unroll
  for (int d = 1; d < 64; d <<= 1){
    int y = __shfl_up(x, d);
    if (lane >= d) x += y;
  }
  if (lane == 63) wsum[wv] = x;
  __syncthreads();
  if (wv == 0){
    int s = (lane < 16) ? wsum[lane] : 0;
    #pragma unroll
    for (int d = 1; d < 16; d <<= 1){
      int y = __shfl_up(s, d);
      if (lane >= d) s += y;
    }
    if (lane < 16) wsum[lane] = s;
  }
  __syncthreads();
  int wbase = wv ? wsum[wv-1] : 0;
  if (i < n) off[i] = wbase + x - v;
  if (tid == 0) bsum[slot] = wsum[15];
}

// ---- scan_add with inlined chunk-base scan ----
__global__ __launch_bounds__(1024) void scan_add(int* __restrict__ o0, int* __restrict__ u0,
                                                 int* __restrict__ o1, int* __restrict__ u1,
                                                 const int* __restrict__ bsum){
  __shared__ int cbs;
  int b = blockIdx.x;
  int tid = threadIdx.x, lane = tid & 63, wv = tid >> 6;
  if (wv == 0){
    int v0 = (lane < CH0) ? bsum[lane] : 0;
    int x0 = v0;
    #pragma unroll
    for (int d = 1; d < 64; d <<= 1){ int y = __shfl_up(x0, d); if (lane >= d) x0 += y; }
    int v1 = (lane < CH1) ? bsum[CH0 + lane] : 0;
    int x1 = v1;
    #pragma unroll
    for (int d = 1; d < 64; d <<= 1){ int y = __shfl_up(x1, d); if (lane >= d) x1 += y; }
    int base = (b < CH0) ? __shfl(x0 - v0, b) : __shfl(x1 - v1, b - CH0);
    if (lane == 0) cbs = base;
    if (b == 0){
      if (lane == CH0-1) o0[NN1] = x0;
      if (lane == CH1-1) o1[NN2] = x1;
    }
  }
  __syncthreads();
  int base = cbs;
  int* off; int* cur; int n, i0;
  if (b < CH0){ off = o0; cur = u0; n = NN1; i0 = b*1024; }
  else        { off = o1; cur = u1; n = NN2; i0 = (b-CH0)*1024; }
  int i = i0 + tid;
  if (i < n){
    int t = off[i] + base;
    off[i] = t; cur[i] = t;
  }
}

// ---- fused CSR fill; computes out-scale inline from outc (no separate scale pass) ----
__global__ void fill2_kernel(const int* __restrict__ s0, const int* __restrict__ d0, int E0,
                             int* __restrict__ cur0, int2* __restrict__ l0, const int* __restrict__ oc0,
                             const int* __restrict__ s1, const int* __restrict__ d1, int E1,
                             int* __restrict__ cur1, int2* __restrict__ l1, const int* __restrict__ oc1){
  int i = blockIdx.x*blockDim.x + threadIdx.x;
  if (i < E0){
    int s = s0[i];
    int c = oc0[s];
    float sc = rsqrtf((float)(c > 1 ? c : 1));
    int p = atomicAdd(&cur0[d0[i]], 1);
    l0[p] = make_int2(s, __float_as_int(sc));
  }
  if (i < E1){
    int s = s1[i];
    int c = oc1[s];
    float sc = rsqrtf((float)(c > 1 ? c : 1));
    int p = atomicAdd(&cur1[d1[i]], 1);
    l1[p] = make_int2(s, __float_as_int(sc));
  }
}

// ---- MFMA GEMM, glds staging, counted-vmcnt pipeline ----
// Optional LN epilogue (LNEP) and deg-count tail blocks (DEGT: blocks >= gemmBlocks
// do degree counting; they backfill CUs as GEMM blocks retire — R9 showed deg-FIRST
// thrashes L2; tail placement spreads the atomic traffic).
template<int K, int N, int BN, int BKT, int TH, bool ABF, bool RELU, bool OBF, bool LNEP, bool DEGT>
__global__ __launch_bounds__(TH) void gemm_glds(const void* __restrict__ Av,
    const u16* __restrict__ BPK, const float* __restrict__ bias,
    void* __restrict__ Cv, int M,
    const float* __restrict__ lng, const float* __restrict__ lnb,
    const int* __restrict__ gs0, const int* __restrict__ gd0, int dE0,
    const int* __restrict__ gs1, const int* __restrict__ gd1, int dE1,
    int* __restrict__ doc0, int* __restrict__ dic0,
    int* __restrict__ doc1, int* __restrict__ dic1, int gemmBlocks)
{
  constexpr int ESZ   = ABF ? 2 : 4;
  constexpr int SLOTS = (BKT*ESZ)/16;      // 16B slots per row
  constexpr int SMSK  = SLOTS - 1;
  constexpr int ROWB  = BKT*ESZ;
  constexpr int TILEB = 128*BKT*ESZ;
  constexpr int NWV   = TH/64;
  constexpr int IW    = TILEB/1024/NWV;    // glds per wave per stage
  constexpr int NT    = K/BKT;
  constexpr int NKH   = BKT/32;            // 32-k steps per tile
  constexpr int NF16  = N/16;
  constexpr int NYB   = N/BN;
  constexpr int WCN   = TH/128;            // waves in col dim
  constexpr int CST   = BN + 8;            // epilogue LDS row stride (u16)
  constexpr int EPB   = (LNEP || OBF) ? 128*CST*2 : 0;
  constexpr int LDSB  = (2*TILEB > EPB) ? 2*TILEB : EPB;
  __shared__ char smem[LDSB];

  if (DEGT && (int)blockIdx.x >= gemmBlocks){
    int i = ((int)blockIdx.x - gemmBlocks)*TH + threadIdx.x;
    if (i < dE0){ atomicAdd(&doc0[gs0[i]], 1); atomicAdd(&dic0[gd0[i]], 1); }
    if (i < dE1){ atomicAdd(&doc1[gs1[i]], 1); atomicAdd(&dic1[gd1[i]], 1); }
    return;
  }

  const int t = threadIdx.x;
  const int lane = t & 63;
  const int wv = t >> 6;
  const int wr = wv / WCN, wc = wv % WCN;

  int b;
  {
    int nb = DEGT ? gemmBlocks : (int)gridDim.x;
    int h = blockIdx.x;
    if (nb >= 8){
      int q = nb >> 3, r = nb & 7, k = h & 7, pos = h >> 3;
      b = (k < r ? k*(q+1) : r*(q+1) + (k-r)*q) + pos;
    } else b = h;
  }
  const int by = b % NYB;
  const int r0 = (b / NYB) * 128;
  const int c0 = by * BN;
  const int m15 = lane & 15, kg = lane >> 4;

  auto stage = [&](int buf, int ti){
    const int k0 = ti*BKT;
    char* bb = smem + buf*TILEB;
    #pragma unroll
    for (int s = 0; s < IW; ++s){
      int i16 = (wv*IW + s)*64 + lane;
      int row = i16 / SLOTS;
      int tt  = i16 & SMSK;
      int tsrc = tt ^ (row & SMSK);
      int grc = min(r0 + row, M-1);
      const char* g = (const char*)Av + ((size_t)grc*K + k0)*ESZ + tsrc*16;
      gl_lds16(g, bb + (wv*IW + s)*1024);
    }
  };

  f32x4 acc[4][4] = {};

  stage(0, 0);

  for (int ti = 0; ti < NT; ++ti){
    s16x8 bfr[NKH][4];
    #pragma unroll
    for (int kh = 0; kh < NKH; ++kh)
      #pragma unroll
      for (int j = 0; j < 4; ++j)
        bfr[kh][j] = *(const s16x8*)(BPK +
          (((size_t)(ti*NKH+kh)*NF16 + (c0>>4) + wc*4 + j)*64 + lane)*8);
    __builtin_amdgcn_sched_barrier(0);

    if (ti + 1 < NT) stage((ti+1)&1, ti+1);
    __builtin_amdgcn_sched_barrier(0);

    // wait for stage(ti); stage(ti+1) + this iter's bfr stay outstanding
    if (ti + 1 < NT){
      constexpr int VW = NKH*4 + IW;
      if constexpr (VW == 8)  asm volatile("s_waitcnt vmcnt(8)");
      else if constexpr (VW == 10) asm volatile("s_waitcnt vmcnt(10)");
      else if constexpr (VW == 12) asm volatile("s_waitcnt vmcnt(12)");
      else if constexpr (VW == 16) asm volatile("s_waitcnt vmcnt(16)");
      else asm volatile("s_waitcnt vmcnt(0)");
    } else {
      constexpr int VB = NKH*4;
      if constexpr (VB == 4) asm volatile("s_waitcnt vmcnt(4)");
      else                   asm volatile("s_waitcnt vmcnt(8)");
    }
    __builtin_amdgcn_s_barrier();
    __builtin_amdgcn_sched_barrier(0);

    const char* bb = smem + (ti&1)*TILEB;
    s16x8 afr[NKH][4];
    #pragma unroll
    for (int kh = 0; kh < NKH; ++kh){
      #pragma unroll
      for (int i = 0; i < 4; ++i){
        int row_l = wr*64 + i*16 + m15;
        if (ABF){
          int s = kh*4 + kg;
          int sw = s ^ (row_l & SMSK);
          afr[kh][i] = *(const s16x8*)(bb + row_l*ROWB + sw*16);
        } else {
          int s0 = kh*8 + kg*2;
          int sw0 = s0 ^ (row_l & SMSK);
          int sw1 = (s0+1) ^ (row_l & SMSK);
          float4 lo = *(const float4*)(bb + row_l*ROWB + sw0*16);
          float4 hi = *(const float4*)(bb + row_l*ROWB + sw1*16);
          u32x4 w;
          w[0] = cvtpk(lo.x, lo.y);
          w[1] = cvtpk(lo.z, lo.w);
          w[2] = cvtpk(hi.x, hi.y);
          w[3] = cvtpk(hi.z, hi.w);
          afr[kh][i] = __builtin_bit_cast(s16x8, w);
        }
      }
    }

    #pragma unroll
    for (int kh = 0; kh < NKH; ++kh)
      #pragma unroll
      for (int i = 0; i < 4; ++i)
        #pragma unroll
        for (int j = 0; j < 4; ++j)
          acc[i][j] = __builtin_amdgcn_mfma_f32_16x16x32_bf16(afr[kh][i], bfr[kh][j], acc[i][j], 0, 0, 0);

    __builtin_amdgcn_sched_barrier(0);
    __builtin_amdgcn_s_barrier();
  }

  __syncthreads();

  if constexpr (LNEP){
    // conv1+LN: repack full 256-col rows into LDS, LN per row, write bf16
    u16* cs = (u16*)smem;
    #pragma unroll
    for (int j = 0; j < 4; ++j){
      int colL = wc*64 + j*16 + m15;
      float bv = bias[colL];
      #pragma unroll
      for (int i = 0; i < 4; ++i){
        int rl = wr*64 + i*16 + kg*4;
        #pragma unroll
        for (int q = 0; q < 4; ++q){
          float v = acc[i][j][q] + bv;
          if (RELU) v = fmaxf(v, 0.f);
          cs[(rl+q)*CST + colL] = f2b(v);
        }
      }
    }
    __syncthreads();
    float4 gv = ((const float4*)lng)[lane];
    float4 bvv = ((const float4*)lnb)[lane];
    constexpr int RPW = 128/NWV;
    #pragma unroll 4
    for (int rr = 0; rr < RPW; ++rr){
      int row = wv*RPW + rr;
      ushort4 u = *(const ushort4*)&cs[row*CST + lane*4];
      float x0=b2f(u.x), x1=b2f(u.y), x2=b2f(u.z), x3=b2f(u.w);
      float s = x0+x1+x2+x3;
      #pragma unroll
      for (int d=1; d<64; d<<=1) s += __shfl_xor(s, d);
      float mu = s * (1.f/256.f);
      float e0=x0-mu, e1=x1-mu, e2=x2-mu, e3=x3-mu;
      float vv = e0*e0 + e1*e1 + e2*e2 + e3*e3;
      #pragma unroll
      for (int d=1; d<64; d<<=1) vv += __shfl_xor(vv, d);
      float inv = rsqrtf(vv*(1.f/256.f) + 1e-5f);
      int gr = r0 + row;
      if (gr < M){
        ushort4 o;
        o.x = f2b(e0*inv*gv.x + bvv.x);
        o.y = f2b(e1*inv*gv.y + bvv.y);
        o.z = f2b(e2*inv*gv.z + bvv.z);
        o.w = f2b(e3*inv*gv.w + bvv.w);
        *(ushort4*)((u16*)Cv + (size_t)gr*256 + lane*4) = o;
      }
    }
  } else if constexpr (OBF){
    // repack epilogue: acc -> LDS u16 [128][CST] -> coalesced 128B/thread stores
    u16* cs = (u16*)smem;
    #pragma unroll
    for (int j = 0; j < 4; ++j){
      int colL = wc*64 + j*16 + m15;
      float bv = bias[c0 + colL];
      #pragma unroll
      for (int i = 0; i < 4; ++i){
        int rl = wr*64 + i*16 + kg*4;
        #pragma unroll
        for (int q = 0; q < 4; ++q){
          float v = acc[i][j][q] + bv;
          if (RELU) v = fmaxf(v, 0.f);
          cs[(rl+q)*CST + colL] = f2b(v);
        }
      }
    }
    __syncthreads();
    constexpr int QPR = BN/64;               // 64-col segments per row
    int rr = t / QPR, hh = t % QPR;
    int go = r0 + rr;
    if (go < M){
      u16* dst = (u16*)Cv + (size_t)go*N + c0 + hh*64;
      const u16* sp = &cs[rr*CST + hh*64];
      #pragma unroll
      for (int c = 0; c < 8; ++c) *(s16x8*)(dst + c*8) = *(const s16x8*)(sp + c*8);
    }
  } else {
    #pragma unroll
    for (int j = 0; j < 4; ++j){
      int colg = c0 + wc*64 + j*16 + m15;
      float bv = bias[colg];
      #pragma unroll
      for (int i = 0; i < 4; ++i){
        int rbase = r0 + wr*64 + i*16 + kg*4;
        #pragma unroll
        for (int q = 0; q < 4; ++q){
          int row = rbase + q;
          if (row < M){
            float v = acc[i][j][q] + bv;
            if (RELU) v = fmaxf(v, 0.f);
            ((float*)Cv)[(size_t)row*N + colg] = v;
          }
        }
      }
    }
  }
}

// ---- CSR pull aggregation: (src,scale) pairs, 8x-unrolled; ri computed from inc ----
__global__ __launch_bounds__(256) void agg_kernel(const u16* __restrict__ X,
    const int* __restrict__ off, const int2* __restrict__ lst,
    const int* __restrict__ inc, u16* __restrict__ out, int nd)
{
  int lane = threadIdx.x & 63, wv = threadIdx.x >> 6;
  int d = blockIdx.x*4 + wv;
  if (d >= nd) return;
  int e0 = off[d], e1 = off[d+1];
  float a0=0.f, a1=0.f, a2=0.f, a3=0.f;
  int e = e0;
  for (; e + 8 <= e1; e += 8){
    int2 pp[8];
    #pragma unroll
    for (int u = 0; u < 8; ++u) pp[u] = lst[e+u];
    ushort4 uu[8];
    #pragma unroll
    for (int u = 0; u < 8; ++u) uu[u] = ((const ushort4*)X)[(size_t)pp[u].x*64 + lane];
    #pragma unroll
    for (int u = 0; u < 8; ++u){
      float sc = __int_as_float(pp[u].y);
      a0 = fmaf(b2f(uu[u].x), sc, a0);
      a1 = fmaf(b2f(uu[u].y), sc, a1);
      a2 = fmaf(b2f(uu[u].z), sc, a2);
      a3 = fmaf(b2f(uu[u].w), sc, a3);
    }
  }
  for (; e < e1; ++e){
    int2 pp = lst[e];
    float sc = __int_as_float(pp.y);
    ushort4 u = ((const ushort4*)X)[(size_t)pp.x*64 + lane];
    a0 = fmaf(b2f(u.x), sc, a0);
    a1 = fmaf(b2f(u.y), sc, a1);
    a2 = fmaf(b2f(u.z), sc, a2);
    a3 = fmaf(b2f(u.w), sc, a3);
  }
  int c = inc[d];
  float r = rsqrtf((float)(c > 1 ? c : 1));
  ushort4 o;
  o.x = f2b(a0*r); o.y = f2b(a1*r); o.z = f2b(a2*r); o.w = f2b(a3*r);
  ((ushort4*)out)[(size_t)d*64 + lane] = o;
}

// ---- row L2-normalize, 128 cols ----
__global__ __launch_bounds__(256) void rownorm_kernel(const float* __restrict__ T,
    float* __restrict__ out, int n)
{
  int lane = threadIdx.x & 63, wv = threadIdx.x >> 6;
  int r = blockIdx.x*4 + wv;
  if (r >= n) return;
  float2 x = ((const float2*)T)[(size_t)r*64 + lane];
  float s = x.x*x.x + x.y*x.y;
  #pragma unroll
  for (int d=1; d<64; d<<=1) s += __shfl_xor(s, d);
  float nrm = sqrtf(s);
  float sc = 1.f / fmaxf(nrm, 1e-12f);
  float2 o; o.x = x.x*sc; o.y = x.y*sc;
  ((float2*)out)[(size_t)r*64 + lane] = o;
}

extern "C" void kernel_launch(void* const* d_in, const int* in_sizes, int n_in,
                              void* d_out, int out_size, void* d_ws, size_t ws_size,
                              hipStream_t stream)
{
  const float* feats = (const float*)d_in[0];
  const int*   b0s   = (const int*)d_in[1];
  const int*   b0d   = (const int*)d_in[2];
  const int*   b1s   = (const int*)d_in[3];
  const int*   b1d   = (const int*)d_in[4];
  const float* W1    = (const float*)d_in[5];
  const float* bias1 = (const float*)d_in[6];
  const float* Wc    = (const float*)d_in[7];
  const float* bc    = (const float*)d_in[8];
  const float* lng   = (const float*)d_in[9];
  const float* lnb   = (const float*)d_in[10];
  const float* Wo    = (const float*)d_in[11];
  const float* bo    = (const float*)d_in[12];
  const int E0 = in_sizes[1];
  const int E1 = in_sizes[3];
  (void)n_in; (void)out_size; (void)ws_size;

  char* p = (char*)d_ws;
  auto alloc = [&](size_t bytes)->void*{ void* q = (void*)p; p += (bytes + 255) & ~(size_t)255; return q; };
  u16*   g1   = (u16*)  alloc((size_t)NN0*HD*2);
  u16*   hb   = (u16*)  alloc((size_t)NN1*HD*2);
  u16*   ag2  = (u16*)  alloc((size_t)NN2*HD*2);
  float* c2   = (float*)alloc((size_t)NN2*OUT_D*4);
  u16*   W1P  = (u16*)  alloc((size_t)HD*IN_DIM*2);
  u16*   WcP  = (u16*)  alloc((size_t)HD*HD*2);
  u16*   WoP  = (u16*)  alloc((size_t)OUT_D*HD*2);
  char* cnt_begin = p;
  int* outc0 = (int*)alloc((size_t)NN0*4);
  int* inc0  = (int*)alloc((size_t)NN1*4);
  int* outc1 = (int*)alloc((size_t)NN1*4);
  int* inc1  = (int*)alloc((size_t)NN2*4);
  char* cnt_end = p;
  int* off0  = (int*)alloc((size_t)(NN1+1)*4);
  int* cur0  = (int*)alloc((size_t)NN1*4);
  int* off1  = (int*)alloc((size_t)(NN2+1)*4);
  int* cur1  = (int*)alloc((size_t)NN2*4);
  int2* lst0 = (int2*)alloc((size_t)800000*8);
  int2* lst1 = (int2*)alloc((size_t)160000*8);
  int* bsum  = (int*)alloc((size_t)(CH0+CH1)*4);

  // K1: zero counters + pack weights
  {
    int nbytes = (int)(cnt_end - cnt_begin);
    int n16 = nbytes >> 4;
    int nzb = (n16 + 255)/256;
    wpz_kernel<<<nzb + 112, 256, 0, stream>>>((int4*)cnt_begin, n16, nzb,
                                              W1, W1P, Wc, WcP, Wo, WoP);
  }

  // K2: GEMM1 (blocks [0,nblk)) + deg-count tail (blocks [nblk, nblk+degBlocks))
  {
    int Emax = E0 > E1 ? E0 : E1;
    int degBlocks = (Emax + 255)/256;
    int nblk = ((NN0+127)/128) * (HD/128);
    gemm_glds<IN_DIM, HD, 128, 32, 256, false, false, true, false, true>
      <<<nblk + degBlocks, 256, 0, stream>>>(feats, W1P, bias1, g1, NN0,
        nullptr, nullptr, b0s, b0d, E0, b1s, b1d, E1,
        outc0, inc0, outc1, inc1, nblk);
  }

  // K3: scan partials
  scan_part<<<CH0+CH1, 1024, 0, stream>>>(inc0, off0, inc1, off1, bsum);

  // K4: add chunk bases
  scan_add<<<CH0+CH1, 1024, 0, stream>>>(off0, cur0, off1, cur1, bsum);

  // K5: CSR fill (out-scale computed inline from outc)
  {
    int Emax = E0 > E1 ? E0 : E1;
    fill2_kernel<<<(Emax+255)/256, 256, 0, stream>>>(b0s, b0d, E0, cur0, lst0, outc0,
                                                     b1s, b1d, E1, cur1, lst1, outc1);
  }

  // K6: agg1 -> hb  (ri from inc0 inline)
  agg_kernel<<<(NN1+3)/4, 256, 0, stream>>>(g1, off0, lst0, inc0, hb, NN1);

  // K7: conv1 = relu(agg1 @ Wc + bc) with fused LayerNorm -> g1
  {
    int nblk = (NN1+127)/128;
    gemm_glds<HD, HD, 256, 64, 512, true, true, false, true, false>
      <<<nblk, 512, 0, stream>>>(hb, WcP, bc, g1, NN1, lng, lnb,
        nullptr, nullptr, 0, nullptr, nullptr, 0,
        nullptr, nullptr, nullptr, nullptr, 0);
  }

  // K8: agg2 -> ag2  (ri from inc1 inline)
  agg_kernel<<<(NN2+3)/4, 256, 0, stream>>>(g1, off1, lst1, inc1, ag2, NN2);

  // K9: conv2 = agg2 @ Wo + bo -> c2 (f32)
  {
    int nblk = (NN2+127)/128;
    gemm_glds<HD, OUT_D, 128, 64, 256, true, false, false, false, false>
      <<<nblk, 256, 0, stream>>>(ag2, WoP, bo, c2, NN2, nullptr, nullptr,
        nullptr, nullptr, 0, nullptr, nullptr, 0,
        nullptr, nullptr, nullptr, nullptr, 0);
  }

  // K10: row L2 normalize -> d_out
  rownorm_kernel<<<(NN2+3)/4, 256, 0, stream>>>(c2, (float*)d_out, NN2);
}